// Round 1
// 1522.390 us; speedup vs baseline: 1.1856x; 1.1856x over previous
//
#include <hip/hip_runtime.h>

// DirectVoxGO forward: trilinear density -> alpha -> per-ray cumprod ->
// trilinear 7ch feature -> MLP(34->16 relu ->3 sigmoid) -> weighted march.
//
// R3 theory: baseline fetched 4.4 GB/launch (8.5x line amplification: SoA
// density + 7 separate k0 channel grids => each 64B line used 4-8B, no
// inter-sample reuse at 2M random points over 16.7M voxels). Fix: on-device
// repack into AoS packed[G^3][8] = {k0[0..6], density} in d_ws (512 MB).
// One fused gather then yields sigma + all 7 features; a (z,z+1) corner pair
// is one fully-used 64B line. Repack is streaming (~1 GB total traffic).

#define G 256
#define G2 65536
#define G3 16777216
#define ACT_SHIFT (-4.5951198501345898f)   // log(1/(1-0.01)-1) = -ln(99)

// ---------------------------------------------------------------------------
// repack: density[G^3] + k0[7][G^3]  ->  packed[G^3][8] (AoS, 32B per voxel)
// Each thread handles 4 consecutive-z voxels: 8 coalesced float4 stream reads,
// 128B contiguous write.
// ---------------------------------------------------------------------------
__global__ __launch_bounds__(256)
void repack_kernel(const float* __restrict__ density,
                   const float* __restrict__ k0,
                   float* __restrict__ packed) {
    const size_t t = (size_t)blockIdx.x * 256 + threadIdx.x;
    const size_t v = t * 4;                       // first voxel of this thread
    float4 d  = *(const float4*)(density + v);
    float4 c0 = *(const float4*)(k0 + 0ull * G3 + v);
    float4 c1 = *(const float4*)(k0 + 1ull * G3 + v);
    float4 c2 = *(const float4*)(k0 + 2ull * G3 + v);
    float4 c3 = *(const float4*)(k0 + 3ull * G3 + v);
    float4 c4 = *(const float4*)(k0 + 4ull * G3 + v);
    float4 c5 = *(const float4*)(k0 + 5ull * G3 + v);
    float4 c6 = *(const float4*)(k0 + 6ull * G3 + v);
    float4* o = (float4*)(packed + v * 8);
    o[0] = make_float4(c0.x, c1.x, c2.x, c3.x);
    o[1] = make_float4(c4.x, c5.x, c6.x, d.x);
    o[2] = make_float4(c0.y, c1.y, c2.y, c3.y);
    o[3] = make_float4(c4.y, c5.y, c6.y, d.y);
    o[4] = make_float4(c0.z, c1.z, c2.z, c3.z);
    o[5] = make_float4(c4.z, c5.z, c6.z, d.z);
    o[6] = make_float4(c0.w, c1.w, c2.w, c3.w);
    o[7] = make_float4(c4.w, c5.w, c6.w, d.w);
}

__device__ __forceinline__ float4 lerp4(float4 a, float4 b, float t) {
    return make_float4(a.x + t * (b.x - a.x),
                       a.y + t * (b.y - a.y),
                       a.z + t * (b.z - a.z),
                       a.w + t * (b.w - a.w));
}

// ---------------------------------------------------------------------------
// Main kernel, packed path. One wave per ray, 4 samples per lane.
// Single fused gather: 16 float4 loads/sample -> sigma + feat[7].
// ---------------------------------------------------------------------------
__global__ __launch_bounds__(256, 2)
void dvgo_fwd_packed(const float* __restrict__ rays_pts,
                     const float* __restrict__ viewdirs,
                     const float* __restrict__ packed,
                     const float* __restrict__ w1,
                     const float* __restrict__ b1,
                     const float* __restrict__ w2,
                     const float* __restrict__ b2,
                     float* __restrict__ out,
                     int n_rays) {
    __shared__ float s_w1[34 * 16];
    __shared__ float s_b1[16];
    __shared__ float s_w2[48];
    __shared__ float s_b2[3];

    const int tid = threadIdx.x;
    for (int i = tid; i < 34 * 16; i += 256) s_w1[i] = w1[i];
    if (tid < 16) s_b1[tid] = b1[tid];
    if (tid < 48) s_w2[tid] = w2[tid];
    if (tid < 3)  s_b2[tid] = b2[tid];
    __syncthreads();

    const int lane = tid & 63;
    const int ray  = blockIdx.x * 4 + (tid >> 6);   // one wave per ray
    if (ray >= n_rays) return;

    // ---- phase 1: 4 samples/lane; fused density+feature trilerp ----
    const float4* pp4 = (const float4*)(rays_pts + (size_t)ray * (256 * 3) + lane * 12);
    float4 p0 = pp4[0];   // s0.xyz, s1.x
    float4 p1 = pp4[1];   // s1.yz, s2.xy
    float4 p2 = pp4[2];   // s2.z, s3.xyz
    float px[4] = {p0.x, p0.w, p1.z, p2.y};
    float py[4] = {p0.y, p1.x, p1.w, p2.z};
    float pz[4] = {p0.z, p1.y, p2.x, p2.w};

    float alpha[4], tcl[4];
    float feat[4][7];
    #pragma unroll
    for (int k = 0; k < 4; ++k) {
        float gx = fminf(fmaxf((px[k] + 1.0f) * 127.5f, 0.0f), 255.0f);
        float gy = fminf(fmaxf((py[k] + 1.0f) * 127.5f, 0.0f), 255.0f);
        float gz = fminf(fmaxf((pz[k] + 1.0f) * 127.5f, 0.0f), 255.0f);
        int ix = min((int)gx, 254);
        int iy = min((int)gy, 254);
        int iz = min((int)gz, 254);
        float fx = gx - (float)ix;
        float fy = gy - (float)iy;
        float fz = gz - (float)iz;
        size_t off = (size_t)((ix << 16) + (iy << 8) + iz) * 8;

        const float4* q00 = (const float4*)(packed + off);                       // (x0,y0)
        const float4* q01 = (const float4*)(packed + off + (size_t)G  * 8);      // (x0,y1)
        const float4* q10 = (const float4*)(packed + off + (size_t)G2 * 8);      // (x1,y0)
        const float4* q11 = (const float4*)(packed + off + (size_t)(G2 + G) * 8);// (x1,y1)

        // each group: [0]=z0 ch0-3, [1]=z0 ch4-7, [2]=z1 ch0-3, [3]=z1 ch4-7
        float4 a0 = q00[0], a1 = q00[1], a2 = q00[2], a3 = q00[3];
        float4 b0 = q01[0], b1v = q01[1], b2v = q01[2], b3 = q01[3];
        float4 c0 = q10[0], c1 = q10[1], c2 = q10[2], c3 = q10[3];
        float4 d0 = q11[0], d1 = q11[1], d2 = q11[2], d3 = q11[3];

        // z-lerp
        float4 m00l = lerp4(a0, a2, fz),  m00h = lerp4(a1, a3, fz);
        float4 m01l = lerp4(b0, b2v, fz), m01h = lerp4(b1v, b3, fz);
        float4 m10l = lerp4(c0, c2, fz),  m10h = lerp4(c1, c3, fz);
        float4 m11l = lerp4(d0, d2, fz),  m11h = lerp4(d1, d3, fz);
        // y-lerp
        float4 e0l = lerp4(m00l, m01l, fy), e0h = lerp4(m00h, m01h, fy);
        float4 e1l = lerp4(m10l, m11l, fy), e1h = lerp4(m10h, m11h, fy);
        // x-lerp
        float4 rl = lerp4(e0l, e1l, fx);  // feat 0..3
        float4 rh = lerp4(e0h, e1h, fx);  // feat 4..6, .w = sigma

        feat[k][0] = rl.x; feat[k][1] = rl.y; feat[k][2] = rl.z; feat[k][3] = rl.w;
        feat[k][4] = rh.x; feat[k][5] = rh.y; feat[k][6] = rh.z;

        float x = rh.w + ACT_SHIFT;
        float sp = fmaxf(x, 0.0f) + log1pf(expf(-fabsf(x)));  // stable softplus
        float t = expf(-sp);                 // = 1 - alpha
        alpha[k] = 1.0f - t;
        tcl[k] = fmaxf(t, 1e-10f);
    }

    // ---- phase 2: exclusive cumprod of tcl across the 256-sample ray ----
    float A[4];
    float lp = 1.0f;
    #pragma unroll
    for (int k = 0; k < 4; ++k) { A[k] = lp; lp *= tcl[k]; }
    float inc = lp;                          // inclusive scan over lane totals
    #pragma unroll
    for (int off = 1; off < 64; off <<= 1) {
        float y = __shfl_up(inc, off, 64);
        if (lane >= off) inc *= y;
    }
    float totalT = __shfl(inc, 63, 64);      // alphainv_cum[..., -1]
    float excl = __shfl_up(inc, 1, 64);
    if (lane == 0) excl = 1.0f;
    float weff[4];
    #pragma unroll
    for (int k = 0; k < 4; ++k) {
        float w = alpha[k] * (A[k] * excl);
        weff[k] = (w > 1e-4f) ? w : 0.0f;    // FAST_COLOR_THRES
    }

    // ---- phase 3: per-ray view-embedding contribution to layer 1 ----
    float vd[3] = {viewdirs[ray * 3 + 0], viewdirs[ray * 3 + 1], viewdirs[ray * 3 + 2]};
    float hpre[16];
    #pragma unroll
    for (int j = 0; j < 16; ++j) hpre[j] = s_b1[j];
    #pragma unroll
    for (int d = 0; d < 3; ++d) {
        #pragma unroll
        for (int j = 0; j < 16; ++j) hpre[j] += vd[d] * s_w1[(7 + d) * 16 + j];
    }
    #pragma unroll
    for (int d = 0; d < 3; ++d) {
        #pragma unroll
        for (int fi = 0; fi < 4; ++fi) {
            float a = vd[d] * (float)(1 << fi);
            float sv = sinf(a);
            float cv = cosf(a);
            const int rs = (10 + d * 4 + fi) * 16;
            const int rc = (22 + d * 4 + fi) * 16;
            #pragma unroll
            for (int j = 0; j < 16; ++j)
                hpre[j] += sv * s_w1[rs + j] + cv * s_w1[rc + j];
        }
    }

    // ---- phase 4: MLP + march (features already in registers) ----
    float acc0 = 0.0f, acc1 = 0.0f, acc2 = 0.0f;
    #pragma unroll
    for (int k = 0; k < 4; ++k) {
        if (weff[k] <= 0.0f) continue;
        float h[16];
        #pragma unroll
        for (int j = 0; j < 16; ++j) h[j] = hpre[j];
        #pragma unroll
        for (int c = 0; c < 7; ++c) {
            float f = feat[k][c];
            #pragma unroll
            for (int j = 0; j < 16; ++j) h[j] += f * s_w1[c * 16 + j];
        }
        float r0 = s_b2[0], r1 = s_b2[1], r2 = s_b2[2];
        #pragma unroll
        for (int j = 0; j < 16; ++j) {
            float hj = fmaxf(h[j], 0.0f);
            r0 += hj * s_w2[j * 3 + 0];
            r1 += hj * s_w2[j * 3 + 1];
            r2 += hj * s_w2[j * 3 + 2];
        }
        r0 = 1.0f / (1.0f + expf(-r0));
        r1 = 1.0f / (1.0f + expf(-r1));
        r2 = 1.0f / (1.0f + expf(-r2));
        acc0 += weff[k] * r0;
        acc1 += weff[k] * r1;
        acc2 += weff[k] * r2;
    }

    // ---- phase 5: wave reduction + output ----
    #pragma unroll
    for (int off = 32; off > 0; off >>= 1) {
        acc0 += __shfl_down(acc0, off, 64);
        acc1 += __shfl_down(acc1, off, 64);
        acc2 += __shfl_down(acc2, off, 64);
    }
    if (lane == 0) {
        out[ray * 3 + 0] = acc0 + totalT;
        out[ray * 3 + 1] = acc1 + totalT;
        out[ray * 3 + 2] = acc2 + totalT;
    }
}

// ---------------------------------------------------------------------------
// Fallback (previous best, SoA gathers) — used only if ws_size < 512 MB.
// ---------------------------------------------------------------------------
__device__ __forceinline__ float trilerp(const float* __restrict__ g,
                                         int base, float fx, float fy, float fz) {
    float c000 = g[base];
    float c001 = g[base + 1];
    float c010 = g[base + G];
    float c011 = g[base + G + 1];
    float c100 = g[base + G2];
    float c101 = g[base + G2 + 1];
    float c110 = g[base + G2 + G];
    float c111 = g[base + G2 + G + 1];
    float c00 = c000 + fz * (c001 - c000);
    float c01 = c010 + fz * (c011 - c010);
    float c10 = c100 + fz * (c101 - c100);
    float c11 = c110 + fz * (c111 - c110);
    float c0 = c00 + fy * (c01 - c00);
    float c1 = c10 + fy * (c11 - c10);
    return c0 + fx * (c1 - c0);
}

__global__ __launch_bounds__(256)
void dvgo_fwd(const float* __restrict__ rays_pts,
              const float* __restrict__ viewdirs,
              const float* __restrict__ density,
              const float* __restrict__ k0,
              const float* __restrict__ w1,
              const float* __restrict__ b1,
              const float* __restrict__ w2,
              const float* __restrict__ b2,
              float* __restrict__ out,
              int n_rays) {
    __shared__ float s_w1[34 * 16];
    __shared__ float s_b1[16];
    __shared__ float s_w2[48];
    __shared__ float s_b2[3];

    const int tid = threadIdx.x;
    for (int i = tid; i < 34 * 16; i += 256) s_w1[i] = w1[i];
    if (tid < 16) s_b1[tid] = b1[tid];
    if (tid < 48) s_w2[tid] = w2[tid];
    if (tid < 3)  s_b2[tid] = b2[tid];
    __syncthreads();

    const int lane = tid & 63;
    const int ray  = blockIdx.x * 4 + (tid >> 6);
    if (ray >= n_rays) return;

    const float4* pp4 = (const float4*)(rays_pts + (size_t)ray * (256 * 3) + lane * 12);
    float4 p0 = pp4[0];
    float4 p1 = pp4[1];
    float4 p2 = pp4[2];
    float px[4] = {p0.x, p0.w, p1.z, p2.y};
    float py[4] = {p0.y, p1.x, p1.w, p2.z};
    float pz[4] = {p0.z, p1.y, p2.x, p2.w};

    int   base[4];
    float fx[4], fy[4], fz[4], alpha[4], tcl[4];
    #pragma unroll
    for (int k = 0; k < 4; ++k) {
        float gx = fminf(fmaxf((px[k] + 1.0f) * 127.5f, 0.0f), 255.0f);
        float gy = fminf(fmaxf((py[k] + 1.0f) * 127.5f, 0.0f), 255.0f);
        float gz = fminf(fmaxf((pz[k] + 1.0f) * 127.5f, 0.0f), 255.0f);
        int ix = min((int)gx, 254);
        int iy = min((int)gy, 254);
        int iz = min((int)gz, 254);
        fx[k] = gx - (float)ix;
        fy[k] = gy - (float)iy;
        fz[k] = gz - (float)iz;
        base[k] = (ix << 16) + (iy << 8) + iz;
        float sigma = trilerp(density, base[k], fx[k], fy[k], fz[k]);
        float x = sigma + ACT_SHIFT;
        float sp = fmaxf(x, 0.0f) + log1pf(expf(-fabsf(x)));
        float t = expf(-sp);
        alpha[k] = 1.0f - t;
        tcl[k] = fmaxf(t, 1e-10f);
    }

    float A[4];
    float lp = 1.0f;
    #pragma unroll
    for (int k = 0; k < 4; ++k) { A[k] = lp; lp *= tcl[k]; }
    float inc = lp;
    #pragma unroll
    for (int off = 1; off < 64; off <<= 1) {
        float y = __shfl_up(inc, off, 64);
        if (lane >= off) inc *= y;
    }
    float totalT = __shfl(inc, 63, 64);
    float excl = __shfl_up(inc, 1, 64);
    if (lane == 0) excl = 1.0f;
    float weff[4];
    #pragma unroll
    for (int k = 0; k < 4; ++k) {
        float w = alpha[k] * (A[k] * excl);
        weff[k] = (w > 1e-4f) ? w : 0.0f;
    }

    float vd[3] = {viewdirs[ray * 3 + 0], viewdirs[ray * 3 + 1], viewdirs[ray * 3 + 2]};
    float hpre[16];
    #pragma unroll
    for (int j = 0; j < 16; ++j) hpre[j] = s_b1[j];
    #pragma unroll
    for (int d = 0; d < 3; ++d) {
        #pragma unroll
        for (int j = 0; j < 16; ++j) hpre[j] += vd[d] * s_w1[(7 + d) * 16 + j];
    }
    #pragma unroll
    for (int d = 0; d < 3; ++d) {
        #pragma unroll
        for (int fi = 0; fi < 4; ++fi) {
            float a = vd[d] * (float)(1 << fi);
            float sv = sinf(a);
            float cv = cosf(a);
            const int rs = (10 + d * 4 + fi) * 16;
            const int rc = (22 + d * 4 + fi) * 16;
            #pragma unroll
            for (int j = 0; j < 16; ++j)
                hpre[j] += sv * s_w1[rs + j] + cv * s_w1[rc + j];
        }
    }

    float acc0 = 0.0f, acc1 = 0.0f, acc2 = 0.0f;
    #pragma unroll
    for (int k = 0; k < 4; ++k) {
        if (weff[k] <= 0.0f) continue;
        float h[16];
        #pragma unroll
        for (int j = 0; j < 16; ++j) h[j] = hpre[j];
        #pragma unroll
        for (int c = 0; c < 7; ++c) {
            float f = trilerp(k0 + (size_t)c * G3, base[k], fx[k], fy[k], fz[k]);
            #pragma unroll
            for (int j = 0; j < 16; ++j) h[j] += f * s_w1[c * 16 + j];
        }
        float r0 = s_b2[0], r1 = s_b2[1], r2 = s_b2[2];
        #pragma unroll
        for (int j = 0; j < 16; ++j) {
            float hj = fmaxf(h[j], 0.0f);
            r0 += hj * s_w2[j * 3 + 0];
            r1 += hj * s_w2[j * 3 + 1];
            r2 += hj * s_w2[j * 3 + 2];
        }
        r0 = 1.0f / (1.0f + expf(-r0));
        r1 = 1.0f / (1.0f + expf(-r1));
        r2 = 1.0f / (1.0f + expf(-r2));
        acc0 += weff[k] * r0;
        acc1 += weff[k] * r1;
        acc2 += weff[k] * r2;
    }

    #pragma unroll
    for (int off = 32; off > 0; off >>= 1) {
        acc0 += __shfl_down(acc0, off, 64);
        acc1 += __shfl_down(acc1, off, 64);
        acc2 += __shfl_down(acc2, off, 64);
    }
    if (lane == 0) {
        out[ray * 3 + 0] = acc0 + totalT;
        out[ray * 3 + 1] = acc1 + totalT;
        out[ray * 3 + 2] = acc2 + totalT;
    }
}

extern "C" void kernel_launch(void* const* d_in, const int* in_sizes, int n_in,
                              void* d_out, int out_size, void* d_ws, size_t ws_size,
                              hipStream_t stream) {
    const float* rays_pts = (const float*)d_in[0];
    const float* viewdirs = (const float*)d_in[1];
    const float* density  = (const float*)d_in[2];
    const float* k0       = (const float*)d_in[3];
    const float* w1       = (const float*)d_in[4];
    const float* b1       = (const float*)d_in[5];
    const float* w2       = (const float*)d_in[6];
    const float* b2       = (const float*)d_in[7];
    float* out = (float*)d_out;

    int n_rays = in_sizes[1] / 3;            // viewdirs is [Nr, 3]
    int blocks = (n_rays + 3) / 4;           // 4 rays (waves) per 256-thread block

    const size_t need = (size_t)G3 * 8 * sizeof(float);   // 512 MB AoS grid
    if (ws_size >= need) {
        float* packed = (float*)d_ws;
        repack_kernel<<<G3 / 1024, 256, 0, stream>>>(density, k0, packed);
        dvgo_fwd_packed<<<blocks, 256, 0, stream>>>(rays_pts, viewdirs, packed,
                                                    w1, b1, w2, b2, out, n_rays);
    } else {
        dvgo_fwd<<<blocks, 256, 0, stream>>>(rays_pts, viewdirs, density, k0,
                                             w1, b1, w2, b2, out, n_rays);
    }
}